// Round 1
// baseline (422.832 us; speedup 1.0000x reference)
//
#include <hip/hip_runtime.h>
#include <hip/hip_bf16.h>

#define NROWS 8192
#define DDIM  512
#define NS    64
#define KK    8
#define HH    240

// ---------------------------------------------------------------------------
// Kernel 1: fused projection + per-slice MLP.
// grid = (NROWS/64, NS/4, 2)  block = 256 (4 waves)
// wave w handles slice s = blockIdx.y*4+w ; lane = row within 64-row tile.
// z = blockIdx.z : 0 -> X -> pred_x, 1 -> Y -> pred_y.
// LDS: X chunk [64][129] (PAD=129 -> (lane+d)%32 bank, 2 lanes/bank = free).
// thetas/W1/b1/W3 accesses are wave-uniform -> scalar loads.
// ---------------------------------------------------------------------------
#define PAD 129
#define CHUNK 128

__global__ __launch_bounds__(256, 4)
void proj_mlp_kernel(const float* __restrict__ X,
                     const float* __restrict__ Y,
                     const float* __restrict__ Xn,
                     const float* __restrict__ Th,
                     const float* __restrict__ W1,
                     const float* __restrict__ b1,
                     const float* __restrict__ W3,
                     const float* __restrict__ b3,
                     const float* __restrict__ sig_p,
                     float* __restrict__ px,   // [NS][NROWS]
                     float* __restrict__ py)   // [NS][NROWS]
{
    __shared__ float xs[64 * PAD];

    const int tid  = threadIdx.x;
    const int w    = __builtin_amdgcn_readfirstlane(tid >> 6);
    const int lane = tid & 63;
    const int s    = blockIdx.y * 4 + w;
    const int n0   = blockIdx.x * 64;
    const int z    = blockIdx.z;

    const float* src = z ? Y : X;
    const int n = n0 + lane;

    float c[KK];
#pragma unroll
    for (int k = 0; k < KK; ++k) c[k] = 0.f;

#pragma unroll 1
    for (int ch = 0; ch < DDIM / CHUNK; ++ch) {
        __syncthreads();
        // stage 64 x 128 floats, coalesced float4 loads
        const float* base = src + (size_t)n0 * DDIM + ch * CHUNK;
#pragma unroll
        for (int i = 0; i < 8; ++i) {
            int f4  = tid + i * 256;          // 0..2047
            int row = f4 >> 5;
            int c4  = f4 & 31;
            float4 v = *(const float4*)(base + row * DDIM + c4 * 4);
            int lo = row * PAD + c4 * 4;
            xs[lo + 0] = v.x; xs[lo + 1] = v.y;
            xs[lo + 2] = v.z; xs[lo + 3] = v.w;
        }
        __syncthreads();

#pragma unroll
        for (int sub = 0; sub < CHUNK / 16; ++sub) {
            float xv[16];
#pragma unroll
            for (int j = 0; j < 16; ++j)
                xv[j] = xs[lane * PAD + sub * 16 + j];
#pragma unroll
            for (int k = 0; k < KK; ++k) {
                const float* th = Th + ((size_t)(s * KK + k)) * DDIM
                                    + ch * CHUNK + sub * 16;
#pragma unroll
                for (int j = 0; j < 16; ++j)
                    c[k] = fmaf(xv[j], th[j], c[k]);
            }
        }
    }

    // optional noise (sigma_noise == 0 in the harness; bits-zero reads as 0.0f)
    float sig = *sig_p;
    if (z == 0 && sig > 0.f) {
#pragma unroll
        for (int k = 0; k < KK; ++k)
            c[k] = fmaf(sig, Xn[(size_t)n * (NS * KK) + s * KK + k], c[k]);
    }

    // per-slice MLP: 8 -> 240 (relu) -> 1 ; all weights wave-uniform
    float pred = b3[s];
#pragma unroll 4
    for (int h = 0; h < HH; ++h) {
        const float* w1 = W1 + ((size_t)(s * HH + h)) * KK;
        float t = b1[s * HH + h];
#pragma unroll
        for (int k = 0; k < KK; ++k) t = fmaf(c[k], w1[k], t);
        t = fmaxf(t, 0.f);
        pred = fmaf(t, W3[s * HH + h], pred);
    }

    float* dst = z ? py : px;
    dst[(size_t)s * NROWS + n] = pred;   // [s][n] -> coalesced
}

// ---------------------------------------------------------------------------
// Kernel 2: per-slice reductions. block s: mean_n(pred_x[s]) and
// logsumexp_n(pred_y[s]); writes term[s] = LSE - log(N) - mean.
// ---------------------------------------------------------------------------
__global__ __launch_bounds__(256)
void reduce_kernel(const float* __restrict__ px,
                   const float* __restrict__ py,
                   float* __restrict__ term)
{
    const int s = blockIdx.x;
    const int t = threadIdx.x;
    const float* prx = px + (size_t)s * NROWS;
    const float* pry = py + (size_t)s * NROWS;

    float sx = 0.f, m = -1e30f, se = 0.f;
    for (int i = t; i < NROWS; i += 256) {
        sx += prx[i];
        float v = pry[i];
        if (v > m) {
            se = se * expf(m - v) + 1.f;
            m = v;
        } else {
            se += expf(v - m);
        }
    }

    __shared__ float smx[256], smm[256], sms[256];
    smx[t] = sx; smm[t] = m; sms[t] = se;
    __syncthreads();
    for (int off = 128; off > 0; off >>= 1) {
        if (t < off) {
            smx[t] += smx[t + off];
            float m1 = smm[t], m2 = smm[t + off];
            float mm = fmaxf(m1, m2);
            sms[t] = sms[t] * expf(m1 - mm) + sms[t + off] * expf(m2 - mm);
            smm[t] = mm;
        }
        __syncthreads();
    }
    if (t == 0) {
        float lse = smm[0] + logf(sms[0]);
        float mx  = smx[0] / (float)NROWS;
        term[s] = lse - logf((float)NROWS) - mx;
    }
}

// ---------------------------------------------------------------------------
// Kernel 3: final mean over 64 slices -> scalar.
// ---------------------------------------------------------------------------
__global__ __launch_bounds__(64)
void final_kernel(const float* __restrict__ term, float* __restrict__ out)
{
    float v = term[threadIdx.x];
#pragma unroll
    for (int off = 32; off > 0; off >>= 1) v += __shfl_down(v, off);
    if (threadIdx.x == 0) out[0] = v * (1.0f / (float)NS);
}

// ---------------------------------------------------------------------------
extern "C" void kernel_launch(void* const* d_in, const int* in_sizes, int n_in,
                              void* d_out, int out_size, void* d_ws, size_t ws_size,
                              hipStream_t stream)
{
    const float* X   = (const float*)d_in[0];
    const float* Y   = (const float*)d_in[1];
    const float* Xn  = (const float*)d_in[2];
    const float* Th  = (const float*)d_in[3];
    const float* W1  = (const float*)d_in[4];
    const float* b1  = (const float*)d_in[5];
    const float* W3  = (const float*)d_in[6];
    const float* b3  = (const float*)d_in[7];
    const float* sig = (const float*)d_in[8];

    float* px   = (float*)d_ws;                       // [NS][NROWS]
    float* py   = px + (size_t)NS * NROWS;            // [NS][NROWS]
    float* term = py + (size_t)NS * NROWS;            // [NS]

    dim3 g1(NROWS / 64, NS / 4, 2);
    proj_mlp_kernel<<<g1, 256, 0, stream>>>(X, Y, Xn, Th, W1, b1, W3, b3,
                                            sig, px, py);
    reduce_kernel<<<NS, 256, 0, stream>>>(px, py, term);
    final_kernel<<<1, 64, 0, stream>>>(term, (float*)d_out);
}

// Round 2
// 164.414 us; speedup vs baseline: 2.5718x; 2.5718x over previous
//
#include <hip/hip_runtime.h>
#include <hip/hip_bf16.h>

#define NROWS 8192
#define DDIM  512
#define NS    64
#define KK    8
#define HH    240
#define LDA   40      // padded bf16 row stride for 32-wide K tiles
#define LDC   129     // padded fp32 row stride for epilogue transpose

typedef __attribute__((ext_vector_type(8))) short bf16x8;
typedef __attribute__((ext_vector_type(4))) float f32x4;

// split fp32 -> (hi, lo) bf16 by mantissa truncation; hi*b + lo*b recovers
// ~2^-16 relative accuracy (dropped lo*lo term), fp32 MFMA accumulate.
__device__ inline void splitf(float x, ushort& hi, ushort& lo) {
    unsigned xb = __float_as_uint(x);
    hi = (ushort)(xb >> 16);
    float rem = x - __uint_as_float(xb & 0xffff0000u);
    lo = (ushort)(__float_as_uint(rem) >> 16);
}

// ---------------------------------------------------------------------------
// Fused kernel: samp = Xcat @ Th^T  (split-bf16 MFMA, fp32 acc)  then per-
// (row,slice) MLP 8->240->1 in the epilogue. Writes pred[s][n] only.
// grid = (16384/128, 512/128) ; block = 256 (4 waves, 2x2 of 64x64).
// ---------------------------------------------------------------------------
__global__ __launch_bounds__(256, 2)
void proj_mlp_kernel(const float* __restrict__ X,
                     const float* __restrict__ Y,
                     const float* __restrict__ Xn,
                     const float* __restrict__ Th,
                     const float* __restrict__ W1,
                     const float* __restrict__ b1,
                     const float* __restrict__ W3,
                     const float* __restrict__ b3,
                     const float* __restrict__ sig_p,
                     float* __restrict__ px,   // [NS][NROWS]
                     float* __restrict__ py)   // [NS][NROWS]
{
    __shared__ __align__(16) char smem[128 * LDC * 4];   // 66048 B
    ushort* ah = (ushort*)smem;            // [128][LDA]
    ushort* al = ah + 128 * LDA;
    ushort* bh = al + 128 * LDA;
    ushort* bl = bh + 128 * LDA;
    float*  cls = (float*)smem;            // [128][LDC] (epilogue reuse)

    const int tid  = threadIdx.x;
    const int w    = __builtin_amdgcn_readfirstlane(tid >> 6);
    const int lane = tid & 63;
    const int bx   = blockIdx.x;           // row block (0..63 X, 64..127 Y)
    const int by   = blockIdx.y;           // col block (16 slices each)

    const float* srcA = (bx < 64) ? (X + (size_t)bx * 128 * DDIM)
                                  : (Y + (size_t)(bx - 64) * 128 * DDIM);
    const float* srcB = Th + (size_t)by * 128 * DDIM;

    const int lrow = tid >> 3;   // 0..31
    const int lc4  = tid & 7;    // 0..7 (float4 column)

    f32x4 acc[4][4];
#pragma unroll
    for (int m = 0; m < 4; ++m)
#pragma unroll
        for (int n = 0; n < 4; ++n) acc[m][n] = (f32x4){0.f, 0.f, 0.f, 0.f};

    const int wr = (w >> 1) * 64;
    const int wc = (w & 1) * 64;
    const int r16 = lane & 15;
    const int k8  = (lane >> 4) * 8;
    const int offA = (wr + r16) * LDA + k8;
    const int offB = (wc + r16) * LDA + k8;

    float4 ra[4], rb[4];
#pragma unroll
    for (int it = 0; it < 4; ++it) {
        ra[it] = *(const float4*)(srcA + (size_t)(lrow + it * 32) * DDIM + lc4 * 4);
        rb[it] = *(const float4*)(srcB + (size_t)(lrow + it * 32) * DDIM + lc4 * 4);
    }

#pragma unroll 1
    for (int kt = 0; kt < DDIM / 32; ++kt) {
        __syncthreads();
        // regs -> split bf16 -> LDS
#pragma unroll
        for (int it = 0; it < 4; ++it) {
            int e = (lrow + it * 32) * LDA + lc4 * 4;
            ushort4 h4, l4;
            splitf(ra[it].x, h4.x, l4.x);
            splitf(ra[it].y, h4.y, l4.y);
            splitf(ra[it].z, h4.z, l4.z);
            splitf(ra[it].w, h4.w, l4.w);
            *(ushort4*)(ah + e) = h4;
            *(ushort4*)(al + e) = l4;
            splitf(rb[it].x, h4.x, l4.x);
            splitf(rb[it].y, h4.y, l4.y);
            splitf(rb[it].z, h4.z, l4.z);
            splitf(rb[it].w, h4.w, l4.w);
            *(ushort4*)(bh + e) = h4;
            *(ushort4*)(bl + e) = l4;
        }
        __syncthreads();

        // prefetch next K tile (hides under MFMA below)
        if (kt + 1 < DDIM / 32) {
            int k0 = (kt + 1) * 32;
#pragma unroll
            for (int it = 0; it < 4; ++it) {
                ra[it] = *(const float4*)(srcA + (size_t)(lrow + it * 32) * DDIM + k0 + lc4 * 4);
                rb[it] = *(const float4*)(srcB + (size_t)(lrow + it * 32) * DDIM + k0 + lc4 * 4);
            }
        }

        bf16x8 aH[4], aL[4], bH[4], bL[4];
#pragma unroll
        for (int m = 0; m < 4; ++m) {
            aH[m] = *(const bf16x8*)(ah + offA + m * 16 * LDA);
            aL[m] = *(const bf16x8*)(al + offA + m * 16 * LDA);
        }
#pragma unroll
        for (int n = 0; n < 4; ++n) {
            bH[n] = *(const bf16x8*)(bh + offB + n * 16 * LDA);
            bL[n] = *(const bf16x8*)(bl + offB + n * 16 * LDA);
        }
#pragma unroll
        for (int m = 0; m < 4; ++m)
#pragma unroll
            for (int n = 0; n < 4; ++n) {
                acc[m][n] = __builtin_amdgcn_mfma_f32_16x16x32_bf16(aH[m], bH[n], acc[m][n], 0, 0, 0);
                acc[m][n] = __builtin_amdgcn_mfma_f32_16x16x32_bf16(aH[m], bL[n], acc[m][n], 0, 0, 0);
                acc[m][n] = __builtin_amdgcn_mfma_f32_16x16x32_bf16(aL[m], bH[n], acc[m][n], 0, 0, 0);
            }
    }

    // ---- epilogue: acc -> LDS [row][col] fp32 -------------------------------
    __syncthreads();
#pragma unroll
    for (int m = 0; m < 4; ++m)
#pragma unroll
        for (int n = 0; n < 4; ++n) {
            int col = wc + n * 16 + r16;
#pragma unroll
            for (int i = 0; i < 4; ++i) {
                int row = wr + m * 16 + (lane >> 4) * 4 + i;
                cls[row * LDC + col] = acc[m][n][i];
            }
        }
    __syncthreads();

    // ---- MLP: wave w owns 4 slices, lane owns rows (lane, lane+64) ----------
    const float sig = *sig_p;
#pragma unroll 1
    for (int si = 0; si < 4; ++si) {
        const int sl = w * 4 + si;
        const int s  = by * 16 + sl;

        float2 c2[KK];
#pragma unroll
        for (int k = 0; k < KK; ++k) {
            c2[k].x = cls[lane * LDC + sl * 8 + k];
            c2[k].y = cls[(lane + 64) * LDC + sl * 8 + k];
        }
        if (sig > 0.f && bx < 64) {
            int n0 = bx * 128 + lane;
#pragma unroll
            for (int k = 0; k < KK; ++k) {
                c2[k].x = fmaf(sig, Xn[(size_t)n0 * (NS * KK) + s * 8 + k], c2[k].x);
                c2[k].y = fmaf(sig, Xn[(size_t)(n0 + 64) * (NS * KK) + s * 8 + k], c2[k].y);
            }
        }

        const float* w1p = W1 + (size_t)s * HH * KK;
        const float* b1p = b1 + s * HH;
        const float* w3p = W3 + s * HH;
        float bv = b3[s];
        float2 pr = {bv, bv};
#pragma unroll 4
        for (int h = 0; h < HH; ++h) {
            float tb = b1p[h];
            float2 t = {tb, tb};
#pragma unroll
            for (int k = 0; k < KK; ++k) {
                float wv = w1p[h * 8 + k];
                t.x = fmaf(c2[k].x, wv, t.x);
                t.y = fmaf(c2[k].y, wv, t.y);
            }
            t.x = fmaxf(t.x, 0.f);
            t.y = fmaxf(t.y, 0.f);
            float w3v = w3p[h];
            pr.x = fmaf(t.x, w3v, pr.x);
            pr.y = fmaf(t.y, w3v, pr.y);
        }

        float* dst;
        int nloc;
        if (bx < 64) { dst = px; nloc = bx * 128 + lane; }
        else         { dst = py; nloc = (bx - 64) * 128 + lane; }
        dst[(size_t)s * NROWS + nloc]      = pr.x;
        dst[(size_t)s * NROWS + nloc + 64] = pr.y;
    }
}

// ---------------------------------------------------------------------------
// Kernel 2: per-slice mean / logsumexp ; term[s] = LSE - log(N) - mean.
// ---------------------------------------------------------------------------
__global__ __launch_bounds__(256)
void reduce_kernel(const float* __restrict__ px,
                   const float* __restrict__ py,
                   float* __restrict__ term)
{
    const int s = blockIdx.x;
    const int t = threadIdx.x;
    const float* prx = px + (size_t)s * NROWS;
    const float* pry = py + (size_t)s * NROWS;

    float sx = 0.f, m = -1e30f, se = 0.f;
    for (int i = t; i < NROWS; i += 256) {
        sx += prx[i];
        float v = pry[i];
        if (v > m) {
            se = se * expf(m - v) + 1.f;
            m = v;
        } else {
            se += expf(v - m);
        }
    }

    __shared__ float smx[256], smm[256], sms[256];
    smx[t] = sx; smm[t] = m; sms[t] = se;
    __syncthreads();
    for (int off = 128; off > 0; off >>= 1) {
        if (t < off) {
            smx[t] += smx[t + off];
            float m1 = smm[t], m2 = smm[t + off];
            float mm = fmaxf(m1, m2);
            sms[t] = sms[t] * expf(m1 - mm) + sms[t + off] * expf(m2 - mm);
            smm[t] = mm;
        }
        __syncthreads();
    }
    if (t == 0) {
        float lse = smm[0] + logf(sms[0]);
        float mx  = smx[0] / (float)NROWS;
        term[s] = lse - logf((float)NROWS) - mx;
    }
}

__global__ __launch_bounds__(64)
void final_kernel(const float* __restrict__ term, float* __restrict__ out)
{
    float v = term[threadIdx.x];
#pragma unroll
    for (int off = 32; off > 0; off >>= 1) v += __shfl_down(v, off);
    if (threadIdx.x == 0) out[0] = v * (1.0f / (float)NS);
}

// ---------------------------------------------------------------------------
extern "C" void kernel_launch(void* const* d_in, const int* in_sizes, int n_in,
                              void* d_out, int out_size, void* d_ws, size_t ws_size,
                              hipStream_t stream)
{
    const float* X   = (const float*)d_in[0];
    const float* Y   = (const float*)d_in[1];
    const float* Xn  = (const float*)d_in[2];
    const float* Th  = (const float*)d_in[3];
    const float* W1  = (const float*)d_in[4];
    const float* b1  = (const float*)d_in[5];
    const float* W3  = (const float*)d_in[6];
    const float* b3  = (const float*)d_in[7];
    const float* sig = (const float*)d_in[8];

    float* px   = (float*)d_ws;                       // [NS][NROWS]
    float* py   = px + (size_t)NS * NROWS;            // [NS][NROWS]
    float* term = py + (size_t)NS * NROWS;            // [NS]

    dim3 g1(128, 4, 1);
    proj_mlp_kernel<<<g1, 256, 0, stream>>>(X, Y, Xn, Th, W1, b1, W3, b3,
                                            sig, px, py);
    reduce_kernel<<<NS, 256, 0, stream>>>(px, py, term);
    final_kernel<<<1, 64, 0, stream>>>(term, (float*)d_out);
}

// Round 3
// 93.856 us; speedup vs baseline: 4.5051x; 1.7518x over previous
//
#include <hip/hip_runtime.h>
#include <hip/hip_bf16.h>

#define NROWS 8192
#define DDIM  512
#define NS    64
#define KK    8
#define HH    240
#define LDA   40      // padded bf16 row stride for GEMM K-tiles
#define SP    136     // samp bf16 LDS pitch (272 B rows: 16B-aligned, 2-way banks)

typedef __attribute__((ext_vector_type(8))) short bf16x8;
typedef __attribute__((ext_vector_type(4))) float f32x4;

// split fp32 -> (hi, lo) bf16 by mantissa truncation; hi*b + lo*b recovers
// ~2^-16 relative accuracy (dropped lo*lo term), fp32 MFMA accumulate.
__device__ inline void splitf(float x, ushort& hi, ushort& lo) {
    unsigned xb = __float_as_uint(x);
    hi = (ushort)(xb >> 16);
    float rem = x - __uint_as_float(xb & 0xffff0000u);
    lo = (ushort)(__float_as_uint(rem) >> 16);
}

// fp32 -> bf16 round-to-nearest-even
__device__ inline ushort f2bf(float x) {
    unsigned u = __float_as_uint(x);
    unsigned r = u + 0x7fffu + ((u >> 16) & 1u);
    return (ushort)(r >> 16);
}

// ---------------------------------------------------------------------------
// Fused: samp = Xcat @ Th^T (split-bf16 MFMA, fp32 acc) -> round to bf16 ->
// layer-1 MFMA (K=8 zero-padded to 32) -> bias+relu+W3 dot on VALU -> pred.
// grid = (128, 4) ; block = 256 (4 waves, 2x2 quadrants of 64x64).
// ---------------------------------------------------------------------------
__global__ __launch_bounds__(256, 2)
void proj_mlp_kernel(const float* __restrict__ X,
                     const float* __restrict__ Y,
                     const float* __restrict__ Xn,
                     const float* __restrict__ Th,
                     const float* __restrict__ W1,
                     const float* __restrict__ b1,
                     const float* __restrict__ W3,
                     const float* __restrict__ b3,
                     const float* __restrict__ sig_p,
                     float* __restrict__ px,   // [NS][NROWS]
                     float* __restrict__ py)   // [NS][NROWS]
{
    __shared__ __align__(16) char smem[4 * 128 * LDA * 2];   // 40960 B
    ushort* ah = (ushort*)smem;            // [128][LDA]
    ushort* al = ah + 128 * LDA;
    ushort* bh = al + 128 * LDA;
    ushort* bl = bh + 128 * LDA;
    ushort* sl = (ushort*)smem;            // samp bf16 [128][SP] (phase 2 reuse)

    const int tid  = threadIdx.x;
    const int w    = __builtin_amdgcn_readfirstlane(tid >> 6);
    const int lane = tid & 63;
    const int bx   = blockIdx.x;           // row block (0..63 X, 64..127 Y)
    const int by   = blockIdx.y;           // col block (16 slices each)

    const float* srcA = (bx < 64) ? (X + (size_t)bx * 128 * DDIM)
                                  : (Y + (size_t)(bx - 64) * 128 * DDIM);
    const float* srcB = Th + (size_t)by * 128 * DDIM;

    const int lrow = tid >> 3;   // 0..31
    const int lc4  = tid & 7;    // 0..7 (float4 column)

    f32x4 acc[4][4];
#pragma unroll
    for (int m = 0; m < 4; ++m)
#pragma unroll
        for (int n = 0; n < 4; ++n) acc[m][n] = (f32x4){0.f, 0.f, 0.f, 0.f};

    const int wr  = (w >> 1) * 64;
    const int wc  = (w & 1) * 64;
    const int r16 = lane & 15;
    const int hi4 = lane >> 4;          // 0..3
    const int offA = (wr + r16) * LDA + hi4 * 8;
    const int offB = (wc + r16) * LDA + hi4 * 8;

    float4 ra[4], rb[4];
#pragma unroll
    for (int it = 0; it < 4; ++it) {
        ra[it] = *(const float4*)(srcA + (size_t)(lrow + it * 32) * DDIM + lc4 * 4);
        rb[it] = *(const float4*)(srcB + (size_t)(lrow + it * 32) * DDIM + lc4 * 4);
    }

#pragma unroll 1
    for (int kt = 0; kt < DDIM / 32; ++kt) {
        __syncthreads();
#pragma unroll
        for (int it = 0; it < 4; ++it) {
            int e = (lrow + it * 32) * LDA + lc4 * 4;
            ushort4 h4, l4;
            splitf(ra[it].x, h4.x, l4.x);
            splitf(ra[it].y, h4.y, l4.y);
            splitf(ra[it].z, h4.z, l4.z);
            splitf(ra[it].w, h4.w, l4.w);
            *(ushort4*)(ah + e) = h4;
            *(ushort4*)(al + e) = l4;
            splitf(rb[it].x, h4.x, l4.x);
            splitf(rb[it].y, h4.y, l4.y);
            splitf(rb[it].z, h4.z, l4.z);
            splitf(rb[it].w, h4.w, l4.w);
            *(ushort4*)(bh + e) = h4;
            *(ushort4*)(bl + e) = l4;
        }
        __syncthreads();

        if (kt + 1 < DDIM / 32) {
            int k0 = (kt + 1) * 32;
#pragma unroll
            for (int it = 0; it < 4; ++it) {
                ra[it] = *(const float4*)(srcA + (size_t)(lrow + it * 32) * DDIM + k0 + lc4 * 4);
                rb[it] = *(const float4*)(srcB + (size_t)(lrow + it * 32) * DDIM + k0 + lc4 * 4);
            }
        }

        bf16x8 aH[4], aL[4], bH[4], bL[4];
#pragma unroll
        for (int m = 0; m < 4; ++m) {
            aH[m] = *(const bf16x8*)(ah + offA + m * 16 * LDA);
            aL[m] = *(const bf16x8*)(al + offA + m * 16 * LDA);
        }
#pragma unroll
        for (int n = 0; n < 4; ++n) {
            bH[n] = *(const bf16x8*)(bh + offB + n * 16 * LDA);
            bL[n] = *(const bf16x8*)(bl + offB + n * 16 * LDA);
        }
#pragma unroll
        for (int m = 0; m < 4; ++m)
#pragma unroll
            for (int n = 0; n < 4; ++n) {
                acc[m][n] = __builtin_amdgcn_mfma_f32_16x16x32_bf16(aH[m], bH[n], acc[m][n], 0, 0, 0);
                acc[m][n] = __builtin_amdgcn_mfma_f32_16x16x32_bf16(aH[m], bL[n], acc[m][n], 0, 0, 0);
                acc[m][n] = __builtin_amdgcn_mfma_f32_16x16x32_bf16(aL[m], bH[n], acc[m][n], 0, 0, 0);
            }
    }

    // ---- phase 2: samp (fp32 acc) -> bf16 LDS [row][col] --------------------
    const float sig = *sig_p;
    const bool addnoise = (sig > 0.f) && (bx < 64);
    const int n0g = ((bx < 64) ? bx : (bx - 64)) * 128;

    __syncthreads();   // GEMM staging LDS now dead
#pragma unroll
    for (int m = 0; m < 4; ++m)
#pragma unroll
        for (int n = 0; n < 4; ++n) {
            int col = wc + n * 16 + r16;
#pragma unroll
            for (int i = 0; i < 4; ++i) {
                int row = wr + m * 16 + hi4 * 4 + i;
                float v = acc[m][n][i];
                if (addnoise)
                    v = fmaf(sig, Xn[(size_t)(n0g + row) * (NS * KK) + by * 128 + col], v);
                sl[row * SP + col] = f2bf(v);
            }
        }
    __syncthreads();

    // ---- phase 3: per-slice MLP on MFMA -------------------------------------
    float* dst = (bx < 64) ? px : py;

#pragma unroll 1
    for (int si = 0; si < 4; ++si) {
        const int sloc = w * 4 + si;
        const int s    = by * 16 + sloc;

        // A-fragments: lanes 0..15 hold samp[m*16+r16][k=0..7]; k=8..31 zero
        bf16x8 a[8];
#pragma unroll
        for (int m = 0; m < 8; ++m) {
            bf16x8 t = {0, 0, 0, 0, 0, 0, 0, 0};
            if (lane < 16)
                t = *(const bf16x8*)(sl + (m * 16 + lane) * SP + sloc * 8);
            a[m] = t;
        }

        float pacc[8][4];
#pragma unroll
        for (int m = 0; m < 8; ++m)
#pragma unroll
            for (int j = 0; j < 4; ++j) pacc[m][j] = 0.f;

        const float* w1p = W1 + (size_t)s * HH * KK;
        const float* b1p = b1 + s * HH;
        const float* w3p = W3 + s * HH;

#pragma unroll 3
        for (int ht = 0; ht < HH / 16; ++ht) {
            const int h = ht * 16 + r16;
            bf16x8 bfr = {0, 0, 0, 0, 0, 0, 0, 0};
            if (lane < 16) {
                const float* wp = w1p + h * 8;
                float4 wa = *(const float4*)wp;
                float4 wb = *(const float4*)(wp + 4);
                bfr[0] = (short)f2bf(wa.x); bfr[1] = (short)f2bf(wa.y);
                bfr[2] = (short)f2bf(wa.z); bfr[3] = (short)f2bf(wa.w);
                bfr[4] = (short)f2bf(wb.x); bfr[5] = (short)f2bf(wb.y);
                bfr[6] = (short)f2bf(wb.z); bfr[7] = (short)f2bf(wb.w);
            }
            const float b1v = b1p[h];
            const float w3v = w3p[h];
            const f32x4 z = (f32x4){0.f, 0.f, 0.f, 0.f};
#pragma unroll
            for (int m = 0; m < 8; ++m) {
                f32x4 t = __builtin_amdgcn_mfma_f32_16x16x32_bf16(a[m], bfr, z, 0, 0, 0);
#pragma unroll
                for (int j = 0; j < 4; ++j) {
                    float v = fmaxf(t[j] + b1v, 0.f);
                    pacc[m][j] = fmaf(v, w3v, pacc[m][j]);
                }
            }
        }

        // reduce over the 16 h-lanes (xor 1,2,4,8 stays inside 16-group)
#pragma unroll
        for (int m = 0; m < 8; ++m)
#pragma unroll
            for (int j = 0; j < 4; ++j) {
                float v = pacc[m][j];
                v += __shfl_xor(v, 1);
                v += __shfl_xor(v, 2);
                v += __shfl_xor(v, 4);
                v += __shfl_xor(v, 8);
                pacc[m][j] = v;
            }

        const float b3v = b3[s];
        if (r16 == 0) {
#pragma unroll
            for (int m = 0; m < 8; ++m) {
                float4 o;
                o.x = pacc[m][0] + b3v;
                o.y = pacc[m][1] + b3v;
                o.z = pacc[m][2] + b3v;
                o.w = pacc[m][3] + b3v;
                int row = m * 16 + hi4 * 4;
                *(float4*)(dst + (size_t)s * NROWS + n0g + row) = o;
            }
        }
    }
}

// ---------------------------------------------------------------------------
// Kernel 2: per-slice mean / logsumexp ; term[s] = LSE - log(N) - mean.
// ---------------------------------------------------------------------------
__global__ __launch_bounds__(256)
void reduce_kernel(const float* __restrict__ px,
                   const float* __restrict__ py,
                   float* __restrict__ term)
{
    const int s = blockIdx.x;
    const int t = threadIdx.x;
    const float* prx = px + (size_t)s * NROWS;
    const float* pry = py + (size_t)s * NROWS;

    float sx = 0.f, m = -1e30f, se = 0.f;
    for (int i = t; i < NROWS; i += 256) {
        sx += prx[i];
        float v = pry[i];
        if (v > m) {
            se = se * expf(m - v) + 1.f;
            m = v;
        } else {
            se += expf(v - m);
        }
    }

    __shared__ float smx[256], smm[256], sms[256];
    smx[t] = sx; smm[t] = m; sms[t] = se;
    __syncthreads();
    for (int off = 128; off > 0; off >>= 1) {
        if (t < off) {
            smx[t] += smx[t + off];
            float m1 = smm[t], m2 = smm[t + off];
            float mm = fmaxf(m1, m2);
            sms[t] = sms[t] * expf(m1 - mm) + sms[t + off] * expf(m2 - mm);
            smm[t] = mm;
        }
        __syncthreads();
    }
    if (t == 0) {
        float lse = smm[0] + logf(sms[0]);
        float mx  = smx[0] / (float)NROWS;
        term[s] = lse - logf((float)NROWS) - mx;
    }
}

__global__ __launch_bounds__(64)
void final_kernel(const float* __restrict__ term, float* __restrict__ out)
{
    float v = term[threadIdx.x];
#pragma unroll
    for (int off = 32; off > 0; off >>= 1) v += __shfl_down(v, off);
    if (threadIdx.x == 0) out[0] = v * (1.0f / (float)NS);
}

// ---------------------------------------------------------------------------
extern "C" void kernel_launch(void* const* d_in, const int* in_sizes, int n_in,
                              void* d_out, int out_size, void* d_ws, size_t ws_size,
                              hipStream_t stream)
{
    const float* X   = (const float*)d_in[0];
    const float* Y   = (const float*)d_in[1];
    const float* Xn  = (const float*)d_in[2];
    const float* Th  = (const float*)d_in[3];
    const float* W1  = (const float*)d_in[4];
    const float* b1  = (const float*)d_in[5];
    const float* W3  = (const float*)d_in[6];
    const float* b3  = (const float*)d_in[7];
    const float* sig = (const float*)d_in[8];

    float* px   = (float*)d_ws;                       // [NS][NROWS]
    float* py   = px + (size_t)NS * NROWS;            // [NS][NROWS]
    float* term = py + (size_t)NS * NROWS;            // [NS]

    dim3 g1(128, 4, 1);
    proj_mlp_kernel<<<g1, 256, 0, stream>>>(X, Y, Xn, Th, W1, b1, W3, b3,
                                            sig, px, py);
    reduce_kernel<<<NS, 256, 0, stream>>>(px, py, term);
    final_kernel<<<1, 64, 0, stream>>>(term, (float*)d_out);
}

// Round 4
// 73.178 us; speedup vs baseline: 5.7781x; 1.2826x over previous
//
#include <hip/hip_runtime.h>
#include <hip/hip_bf16.h>

#define NROWS 8192
#define DDIM  512
#define NS    64
#define KK    8
#define HH    240
#define LDA   40      // bf16 staging pitch for 32-wide K tiles
#define SP    136     // samp bf16 pitch (16 slices * 8 k + pad)

typedef __attribute__((ext_vector_type(8))) short bf16x8;
typedef __attribute__((ext_vector_type(4))) float f32x4;

// fp32 -> bf16 round-to-nearest-even
__device__ inline ushort f2bf(float x) {
    unsigned u = __float_as_uint(x);
    unsigned r = u + 0x7fffu + ((u >> 16) & 1u);
    return (ushort)(r >> 16);
}

// ---------------------------------------------------------------------------
// Kernel 0: pre-pack W1 to bf16 (frag-ready: [s][h][k] contiguous 8 bf16).
// ---------------------------------------------------------------------------
__global__ __launch_bounds__(256)
void pack_w1_kernel(const float* __restrict__ W1, ushort* __restrict__ W1b)
{
    int i = (blockIdx.x * 256 + threadIdx.x) * 4;   // 30720 threads * 4
    float4 v = *(const float4*)(W1 + i);
    ushort4 o;
    o.x = f2bf(v.x); o.y = f2bf(v.y); o.z = f2bf(v.z); o.w = f2bf(v.w);
    *(ushort4*)(W1b + i) = o;
}

// ---------------------------------------------------------------------------
// Main fused kernel: samp = bf16(Xcat) @ bf16(Th)^T (MFMA, fp32 acc) ->
// bf16 samp in LDS -> layer-1 MFMA (b1 folded into C-init) -> relu+W3 fma ->
// 16-lane reduce -> pred[s][n].
// grid = (256, 4) : bx (64-row tiles, 0..127 X / 128..255 Y), by (16 slices).
// block = 256 (4 waves as 2x2 over 64 rows x 128 cols).
// ---------------------------------------------------------------------------
__global__ __launch_bounds__(256, 4)
void proj_mlp_kernel(const float* __restrict__ X,
                     const float* __restrict__ Y,
                     const float* __restrict__ Xn,
                     const float* __restrict__ Th,
                     const ushort* __restrict__ W1b,
                     const float* __restrict__ b1,
                     const float* __restrict__ W3,
                     const float* __restrict__ b3,
                     const float* __restrict__ sig_p,
                     float* __restrict__ px,   // [NS][NROWS]
                     float* __restrict__ py)   // [NS][NROWS]
{
    __shared__ __align__(16) char smem[64 * SP * 2];   // 17408 B
    ushort* aT = (ushort*)smem;            // [64][LDA]
    ushort* bT = aT + 64 * LDA;            // [128][LDA]
    ushort* sl = (ushort*)smem;            // samp [64][SP] (phase-2 reuse)

    const int tid  = threadIdx.x;
    const int w    = __builtin_amdgcn_readfirstlane(tid >> 6);
    const int lane = tid & 63;
    const int bx   = blockIdx.x;           // 0..127 X rows, 128..255 Y rows
    const int by   = blockIdx.y;           // 16-slice group

    const bool isX = (bx < 128);
    const int  bxl = isX ? bx : (bx - 128);
    const float* srcA = (isX ? X : Y) + (size_t)bxl * 64 * DDIM;
    const float* srcB = Th + (size_t)by * 128 * DDIM;

    f32x4 acc[2][4];
#pragma unroll
    for (int m = 0; m < 2; ++m)
#pragma unroll
        for (int n = 0; n < 4; ++n) acc[m][n] = (f32x4){0.f, 0.f, 0.f, 0.f};

    const int wr  = (w >> 1) * 32;        // wave row-origin (0/32)
    const int wc  = (w & 1) * 64;         // wave col-origin (0/64)
    const int r16 = lane & 15;
    const int hi4 = lane >> 4;            // 0..3
    const int offA = (wr + r16) * LDA + hi4 * 8;
    const int offB = (wc + r16) * LDA + hi4 * 8;

    // staging: A 2 float4/thread, B 4 float4/thread
    float4 ra[2], rb[4];
#pragma unroll
    for (int i = 0; i < 2; ++i) {
        int f = tid + i * 256;            // 0..511
        ra[i] = *(const float4*)(srcA + (size_t)(f >> 3) * DDIM + (f & 7) * 4);
    }
#pragma unroll
    for (int i = 0; i < 4; ++i) {
        int f = tid + i * 256;            // 0..1023
        rb[i] = *(const float4*)(srcB + (size_t)(f >> 3) * DDIM + (f & 7) * 4);
    }

#pragma unroll 1
    for (int kt = 0; kt < DDIM / 32; ++kt) {
        __syncthreads();
#pragma unroll
        for (int i = 0; i < 2; ++i) {
            int f = tid + i * 256;
            ushort4 o;
            o.x = f2bf(ra[i].x); o.y = f2bf(ra[i].y);
            o.z = f2bf(ra[i].z); o.w = f2bf(ra[i].w);
            *(ushort4*)(aT + (f >> 3) * LDA + (f & 7) * 4) = o;
        }
#pragma unroll
        for (int i = 0; i < 4; ++i) {
            int f = tid + i * 256;
            ushort4 o;
            o.x = f2bf(rb[i].x); o.y = f2bf(rb[i].y);
            o.z = f2bf(rb[i].z); o.w = f2bf(rb[i].w);
            *(ushort4*)(bT + (f >> 3) * LDA + (f & 7) * 4) = o;
        }
        __syncthreads();

        if (kt + 1 < DDIM / 32) {
            const int k0 = (kt + 1) * 32;
#pragma unroll
            for (int i = 0; i < 2; ++i) {
                int f = tid + i * 256;
                ra[i] = *(const float4*)(srcA + (size_t)(f >> 3) * DDIM + k0 + (f & 7) * 4);
            }
#pragma unroll
            for (int i = 0; i < 4; ++i) {
                int f = tid + i * 256;
                rb[i] = *(const float4*)(srcB + (size_t)(f >> 3) * DDIM + k0 + (f & 7) * 4);
            }
        }

        bf16x8 af[2], bf[4];
#pragma unroll
        for (int m = 0; m < 2; ++m) af[m] = *(const bf16x8*)(aT + offA + m * 16 * LDA);
#pragma unroll
        for (int n = 0; n < 4; ++n) bf[n] = *(const bf16x8*)(bT + offB + n * 16 * LDA);
#pragma unroll
        for (int m = 0; m < 2; ++m)
#pragma unroll
            for (int n = 0; n < 4; ++n)
                acc[m][n] = __builtin_amdgcn_mfma_f32_16x16x32_bf16(af[m], bf[n], acc[m][n], 0, 0, 0);
    }

    // ---- phase 2: acc (+noise) -> bf16 samp LDS [row][col] ------------------
    const float sig = *sig_p;
    const bool addnoise = (sig > 0.f) && isX;
    const int n0g = bxl * 64;

    __syncthreads();   // staging LDS dead
#pragma unroll
    for (int m = 0; m < 2; ++m)
#pragma unroll
        for (int n = 0; n < 4; ++n) {
            int col = wc + n * 16 + r16;
#pragma unroll
            for (int j = 0; j < 4; ++j) {
                int row = wr + m * 16 + hi4 * 4 + j;
                float v = acc[m][n][j];
                if (addnoise)
                    v = fmaf(sig, Xn[(size_t)(n0g + row) * (NS * KK) + by * 128 + col], v);
                sl[row * SP + col] = f2bf(v);
            }
        }
    __syncthreads();

    // ---- phase 3: per-slice MLP on MFMA (b1 in C-init) ----------------------
    float* dst = isX ? px : py;

#pragma unroll 1
    for (int si = 0; si < 4; ++si) {
        const int sloc = w * 4 + si;
        const int s    = by * 16 + sloc;

        bf16x8 a[4];
#pragma unroll
        for (int m = 0; m < 4; ++m) {
            bf16x8 t = {0, 0, 0, 0, 0, 0, 0, 0};
            if (lane < 16)
                t = *(const bf16x8*)(sl + (m * 16 + lane) * SP + sloc * 8);
            a[m] = t;
        }

        float pacc[4][4];
#pragma unroll
        for (int m = 0; m < 4; ++m)
#pragma unroll
            for (int j = 0; j < 4; ++j) pacc[m][j] = 0.f;

        const ushort* w1p = W1b + (size_t)s * HH * KK;
        const float*  b1p = b1 + s * HH;
        const float*  w3p = W3 + s * HH;

#pragma unroll 3
        for (int ht = 0; ht < HH / 16; ++ht) {
            const int h = ht * 16 + r16;
            bf16x8 bfr = {0, 0, 0, 0, 0, 0, 0, 0};
            if (lane < 16)
                bfr = *(const bf16x8*)(w1p + h * 8);
            const float b1v = b1p[h];
            const float w3v = w3p[h];
            const f32x4 z = (f32x4){b1v, b1v, b1v, b1v};
#pragma unroll
            for (int m = 0; m < 4; ++m) {
                f32x4 t = __builtin_amdgcn_mfma_f32_16x16x32_bf16(a[m], bfr, z, 0, 0, 0);
#pragma unroll
                for (int j = 0; j < 4; ++j)
                    pacc[m][j] = fmaf(fmaxf(t[j], 0.f), w3v, pacc[m][j]);
            }
        }

        // reduce over 16 h-lanes
#pragma unroll
        for (int m = 0; m < 4; ++m)
#pragma unroll
            for (int j = 0; j < 4; ++j) {
                float v = pacc[m][j];
                v += __shfl_xor(v, 1);
                v += __shfl_xor(v, 2);
                v += __shfl_xor(v, 4);
                v += __shfl_xor(v, 8);
                pacc[m][j] = v;
            }

        const float b3v = b3[s];
        if (r16 == 0) {
#pragma unroll
            for (int m = 0; m < 4; ++m) {
                float4 o;
                o.x = pacc[m][0] + b3v;
                o.y = pacc[m][1] + b3v;
                o.z = pacc[m][2] + b3v;
                o.w = pacc[m][3] + b3v;
                *(float4*)(dst + (size_t)s * NROWS + n0g + m * 16 + hi4 * 4) = o;
            }
        }
    }
}

// ---------------------------------------------------------------------------
// Kernel 2: partial per-(slice, quarter) reductions. grid 256.
// part[b] = {sum_x, max_y, expsum_y, 0}
// ---------------------------------------------------------------------------
__global__ __launch_bounds__(256)
void reduce1_kernel(const float* __restrict__ px,
                    const float* __restrict__ py,
                    float4* __restrict__ part)
{
    const int s = blockIdx.x >> 2;
    const int q = blockIdx.x & 3;
    const int t = threadIdx.x;
    const float* prx = px + (size_t)s * NROWS + q * 2048;
    const float* pry = py + (size_t)s * NROWS + q * 2048;

    float sx = 0.f, m = -1e30f, se = 0.f;
#pragma unroll
    for (int i = 0; i < 8; ++i) {
        int idx = t + i * 256;
        sx += prx[idx];
        float v = pry[idx];
        if (v > m) {
            se = se * __expf(m - v) + 1.f;
            m = v;
        } else {
            se += __expf(v - m);
        }
    }

    __shared__ float smx[256], smm[256], sms[256];
    smx[t] = sx; smm[t] = m; sms[t] = se;
    __syncthreads();
    for (int off = 128; off > 0; off >>= 1) {
        if (t < off) {
            smx[t] += smx[t + off];
            float m1 = smm[t], m2 = smm[t + off];
            float mm = fmaxf(m1, m2);
            sms[t] = sms[t] * __expf(m1 - mm) + sms[t + off] * __expf(m2 - mm);
            smm[t] = mm;
        }
        __syncthreads();
    }
    if (t == 0) part[blockIdx.x] = (float4){smx[0], smm[0], sms[0], 0.f};
}

// ---------------------------------------------------------------------------
// Kernel 3: combine partials per slice, then mean over slices -> scalar.
// ---------------------------------------------------------------------------
__global__ __launch_bounds__(64)
void final_kernel(const float4* __restrict__ part, float* __restrict__ out)
{
    const int s = threadIdx.x;
    float sum = 0.f, m = -1e30f, se = 0.f;
#pragma unroll
    for (int q = 0; q < 4; ++q) {
        float4 p = part[s * 4 + q];
        sum += p.x;
        float mm = fmaxf(m, p.y);
        se = se * __expf(m - mm) + p.z * __expf(p.y - mm);
        m = mm;
    }
    float lse  = m + logf(se);
    float term = lse - logf((float)NROWS) - sum / (float)NROWS;
#pragma unroll
    for (int off = 32; off > 0; off >>= 1) term += __shfl_down(term, off);
    if (s == 0) out[0] = term * (1.0f / (float)NS);
}

// ---------------------------------------------------------------------------
extern "C" void kernel_launch(void* const* d_in, const int* in_sizes, int n_in,
                              void* d_out, int out_size, void* d_ws, size_t ws_size,
                              hipStream_t stream)
{
    const float* X   = (const float*)d_in[0];
    const float* Y   = (const float*)d_in[1];
    const float* Xn  = (const float*)d_in[2];
    const float* Th  = (const float*)d_in[3];
    const float* W1  = (const float*)d_in[4];
    const float* b1  = (const float*)d_in[5];
    const float* W3  = (const float*)d_in[6];
    const float* b3  = (const float*)d_in[7];
    const float* sig = (const float*)d_in[8];

    float*  px   = (float*)d_ws;                       // [NS][NROWS]
    float*  py   = px + (size_t)NS * NROWS;            // [NS][NROWS]
    ushort* W1b  = (ushort*)(py + (size_t)NS * NROWS); // [NS][HH][KK] bf16
    float4* part = (float4*)(W1b + (size_t)NS * HH * KK);

    pack_w1_kernel<<<NS * HH * KK / 1024, 256, 0, stream>>>(W1, W1b);

    dim3 g1(256, 4, 1);
    proj_mlp_kernel<<<g1, 256, 0, stream>>>(X, Y, Xn, Th, W1b, b1, W3, b3,
                                            sig, px, py);
    reduce1_kernel<<<256, 256, 0, stream>>>(px, py, part);
    final_kernel<<<1, 64, 0, stream>>>(part, (float*)d_out);
}